// Round 1
// baseline (3724.874 us; speedup 1.0000x reference)
//
#include <hip/hip_runtime.h>
#include <hip/hip_fp16.h>

#define BB 16
#define NN 1024
#define DD 256

typedef _Float16 h8 __attribute__((ext_vector_type(8)));
typedef _Float16 hv4 __attribute__((ext_vector_type(4)));
typedef float f32x4 __attribute__((ext_vector_type(4)));

#if __has_builtin(__builtin_amdgcn_exp2f)
#define EXP2F(x) __builtin_amdgcn_exp2f(x)
#else
#define EXP2F(x) exp2f(x)
#endif
#if __has_builtin(__builtin_amdgcn_logf)
#define LOG2F(x) __builtin_amdgcn_logf(x)
#else
#define LOG2F(x) log2f(x)
#endif

// log2-domain constants
// logK = -(C_content + 0.02*|i-j|/1023)/0.1 ;  C_content = relu(1-S)/0.1
// A2 = log2e * (-100*relu(1-S))  (content part, stored fp16)
// pos contribution (log2): -CPOS2*|i-j|
__device__ __constant__ float cdummy; // keep nothing weird
constexpr float K_A2  = -144.26950408889634f;                 // -100*log2(e)
constexpr float CPOS2 = (float)(0.2 * 1.4426950408889634 / 1023.0);
constexpr float C1    = 0.06931471805599453f;                 // ln2/10 : C_content = -C1*A2
constexpr float BASE2 = -10.0f;                               // log2(1/1024 + 1e-12)

__device__ __forceinline__ float waveReduceSum(float v) {
#pragma unroll
  for (int o = 32; o; o >>= 1) v += __shfl_xor(v, o);
  return v;
}

// ---------------- K1: normalize rows of X and Y -> fp16 ----------------
__global__ __launch_bounds__(256) void normalize_kernel(
    const float* __restrict__ X, const float* __restrict__ Y,
    _Float16* __restrict__ Xh, _Float16* __restrict__ Yh) {
  int wave = threadIdx.x >> 6;
  int lane = threadIdx.x & 63;
  int row = blockIdx.x * 4 + wave;           // 0 .. 2*BB*NN-1
  const float* src;
  _Float16* dst;
  if (row < BB * NN) { src = X + (size_t)row * DD; dst = Xh + (size_t)row * DD; }
  else { int r2 = row - BB * NN; src = Y + (size_t)r2 * DD; dst = Yh + (size_t)r2 * DD; }
  float4 v = *(const float4*)(src + lane * 4);
  float ss = v.x * v.x + v.y * v.y + v.z * v.z + v.w * v.w;
  ss = waveReduceSum(ss);
  float sc = 1.0f / fmaxf(sqrtf(ss), 1e-12f);
  hv4 hv;
  hv[0] = (_Float16)(v.x * sc); hv[1] = (_Float16)(v.y * sc);
  hv[2] = (_Float16)(v.z * sc); hv[3] = (_Float16)(v.w * sc);
  *(hv4*)(dst + lane * 4) = hv;
}

// ---------------- K2: S = Ah . Bh^T per batch, write A2 = K_A2*relu(1-S) (fp16) ----
// grid (NN/128, NN/128, BB), block 256 (4 waves), tile 128x128, wave tile 32x128
__global__ __launch_bounds__(256) void gemm_a2_kernel(
    const _Float16* __restrict__ Ah, const _Float16* __restrict__ Bh,
    _Float16* __restrict__ Out) {
  const int b = blockIdx.z;
  const int I0 = blockIdx.y * 128;
  const int J0 = blockIdx.x * 128;
  const int lane = threadIdx.x & 63;
  const int wave = threadIdx.x >> 6;
  const int m = lane & 15, quad = lane >> 4;
  const _Float16* Abase = Ah + ((size_t)b * NN + I0 + wave * 32) * DD;
  const _Float16* Bbase = Bh + ((size_t)b * NN + J0) * DD;
  f32x4 acc[2][8] = {};
  for (int k0 = 0; k0 < DD; k0 += 32) {
    int koff = k0 + quad * 8;
    h8 a0 = *(const h8*)(Abase + (size_t)m * DD + koff);
    h8 a1 = *(const h8*)(Abase + (size_t)(m + 16) * DD + koff);
#pragma unroll
    for (int t = 0; t < 8; ++t) {
      h8 bf = *(const h8*)(Bbase + (size_t)(t * 16 + m) * DD + koff);
      acc[0][t] = __builtin_amdgcn_mfma_f32_16x16x32_f16(a0, bf, acc[0][t], 0, 0, 0);
      acc[1][t] = __builtin_amdgcn_mfma_f32_16x16x32_f16(a1, bf, acc[1][t], 0, 0, 0);
    }
  }
  _Float16* Ob = Out + ((size_t)b * NN + I0 + wave * 32) * NN + J0;
#pragma unroll
  for (int a = 0; a < 2; ++a)
#pragma unroll
    for (int t = 0; t < 8; ++t)
#pragma unroll
      for (int r = 0; r < 4; ++r) {
        int row = a * 16 + quad * 4 + r;
        int col = t * 16 + m;
        float s = acc[a][t][r];
        Ob[(size_t)row * NN + col] = (_Float16)(K_A2 * fmaxf(1.0f - s, 0.0f));
      }
}

// ---------------- Sinkhorn persistent kernel ----------------
__device__ __forceinline__ void group_barrier(unsigned* ctr, unsigned target) {
  __syncthreads();
  if (threadIdx.x == 0) {
    __threadfence();
    __hip_atomic_fetch_add(ctr, 1u, __ATOMIC_RELEASE, __HIP_MEMORY_SCOPE_AGENT);
    while (__hip_atomic_load(ctr, __ATOMIC_ACQUIRE, __HIP_MEMORY_SCOPE_AGENT) < target) {
      __builtin_amdgcn_s_sleep(4);
    }
    __threadfence();
  }
  __syncthreads();
}

// one logsumexp pass: vout[i] = BASE2 - lse2_j( P[i][j] + vin[j] - CPOS2*|i-j| )
__device__ __forceinline__ void lse_pass(const _Float16* __restrict__ P,
                                         const float* __restrict__ vin,
                                         float* __restrict__ vout, int sub) {
  const int lane = threadIdx.x & 63;
  const int wave = threadIdx.x >> 6;           // 0..7
  const int wg = sub * 8 + wave;               // 0..127
  const int j0 = lane * 8;
  float4 g0 = *(const float4*)(vin + j0);
  float4 g1 = *(const float4*)(vin + j0 + 4);
  float4 g2 = *(const float4*)(vin + 512 + j0);
  float4 g3 = *(const float4*)(vin + 512 + j0 + 4);
  float gv[16] = {g0.x, g0.y, g0.z, g0.w, g1.x, g1.y, g1.z, g1.w,
                  g2.x, g2.y, g2.z, g2.w, g3.x, g3.y, g3.z, g3.w};
  for (int s = 0; s < 8; ++s) {
    int i = wg + s * 128;
    const _Float16* row = P + (size_t)i * NN;
    h8 qa = *(const h8*)(row + j0);
    h8 qb = *(const h8*)(row + 512 + j0);
    float x[16];
    float fi = (float)i;
#pragma unroll
    for (int k = 0; k < 8; ++k) {
      float da = fabsf(fi - (float)(j0 + k));
      float db = fabsf(fi - (float)(512 + j0 + k));
      x[k]     = (float)qa[k] + fmaf(-CPOS2, da, gv[k]);
      x[8 + k] = (float)qb[k] + fmaf(-CPOS2, db, gv[8 + k]);
    }
    float m = x[0];
#pragma unroll
    for (int k = 1; k < 16; ++k) m = fmaxf(m, x[k]);
#pragma unroll
    for (int o = 32; o; o >>= 1) m = fmaxf(m, __shfl_xor(m, o));
    float sa = 0.f;
#pragma unroll
    for (int k = 0; k < 16; ++k) sa += EXP2F(x[k] - m);
    sa = waveReduceSum(sa);
    if (lane == 0) vout[i] = BASE2 - (m + LOG2F(sa));
  }
}

// grid 256 blocks x 512 thr: batch = bid&15 (XCD affinity), sub = bid>>4 (0..15)
__global__ __launch_bounds__(512, 2) void sinkhorn_kernel(
    const _Float16* __restrict__ A2, const _Float16* __restrict__ A2T,
    float* __restrict__ F, float* __restrict__ G, unsigned* __restrict__ bar) {
  const int batch = blockIdx.x & 15;
  const int sub = blockIdx.x >> 4;
  const _Float16* Pa = A2 + (size_t)batch * NN * NN;
  const _Float16* Pt = A2T + (size_t)batch * NN * NN;
  float* Fb = F + batch * NN;
  float* Gb = G + batch * NN;
  unsigned* ctr = bar + batch;
  unsigned tgt = 0;
  for (int it = 0; it < 50; ++it) {
    lse_pass(Pa, Gb, Fb, sub);
    tgt += 16; group_barrier(ctr, tgt);
    lse_pass(Pt, Fb, Gb, sub);
    tgt += 16; group_barrier(ctr, tgt);
  }
}

// ---------------- K5: marginals (+ L_main on the row pass) ----------------
// outS[i] = sum_j T ; outL[i] = sum_j T * C_content  (C_content from content part only)
__global__ __launch_bounds__(512) void marginals_kernel(
    const _Float16* __restrict__ P, const float* __restrict__ rowv,
    const float* __restrict__ colv, float* __restrict__ outS, float* __restrict__ outL) {
  const int b = blockIdx.y, sub = blockIdx.x;  // sub 0..7
  const _Float16* Pb = P + (size_t)b * NN * NN;
  const float* rv = rowv + b * NN;
  const float* cv = colv + b * NN;
  const int lane = threadIdx.x & 63;
  const int wave = threadIdx.x >> 6;
  const int wg = sub * 8 + wave;               // 0..63
  const int j0 = lane * 8;
  float4 g0 = *(const float4*)(cv + j0);
  float4 g1 = *(const float4*)(cv + j0 + 4);
  float4 g2 = *(const float4*)(cv + 512 + j0);
  float4 g3 = *(const float4*)(cv + 512 + j0 + 4);
  float gv[16] = {g0.x, g0.y, g0.z, g0.w, g1.x, g1.y, g1.z, g1.w,
                  g2.x, g2.y, g2.z, g2.w, g3.x, g3.y, g3.z, g3.w};
  for (int s = 0; s < 16; ++s) {
    int i = wg + s * 64;
    float rvi = rv[i];
    const _Float16* row = Pb + (size_t)i * NN;
    h8 qa = *(const h8*)(row + j0);
    h8 qb = *(const h8*)(row + 512 + j0);
    float fi = (float)i;
    float sr = 0.f, sl = 0.f;
#pragma unroll
    for (int k = 0; k < 8; ++k) {
      float a2a = (float)qa[k];
      float a2b = (float)qb[k];
      float da = fabsf(fi - (float)(j0 + k));
      float db = fabsf(fi - (float)(512 + j0 + k));
      float Ta = EXP2F(a2a + rvi + fmaf(-CPOS2, da, gv[k]));
      float Tb = EXP2F(a2b + rvi + fmaf(-CPOS2, db, gv[8 + k]));
      sr += Ta + Tb;
      sl = fmaf(Ta, a2a, sl);
      sl = fmaf(Tb, a2b, sl);
    }
    sr = waveReduceSum(sr);
    sl = waveReduceSum(sl);
    if (lane == 0) { outS[b * NN + i] = sr; outL[b * NN + i] = -C1 * sl; }
  }
}

// ---------------- K6: num = T @ Emb ; accumulate sum((Ref - num/denom)^2) ----------
// grid (NN/64, BB), block 512. rowgroup rg=t>>8 covers 32 rows, d = t&255.
__global__ __launch_bounds__(512) void bary_kernel(
    const _Float16* __restrict__ P, const float* __restrict__ rowv,
    const float* __restrict__ colv, const float* __restrict__ denom,
    const float* __restrict__ Emb, const float* __restrict__ Ref,
    float* __restrict__ baryAcc) {
  const int b = blockIdx.y;
  const int I0 = blockIdx.x * 64;
  const _Float16* Pb = P + (size_t)b * NN * NN;
  const float* rv = rowv + b * NN;
  const float* cvv = colv + b * NN;
  const float* dn = denom + b * NN;
  const float* Eb = Emb + (size_t)b * NN * DD;
  const float* Rb = Ref + (size_t)b * NN * DD;
  __shared__ float Tl[64 * 64];
  __shared__ float red[8];
  const int t = threadIdx.x;
  const int rg = t >> 8, d = t & 255;
  float acc[32];
#pragma unroll
  for (int k = 0; k < 32; ++k) acc[k] = 0.f;
  for (int ch = 0; ch < 16; ++ch) {
    __syncthreads();
    {
      int jj = t & 63;
      int jabs = ch * 64 + jj;
      float gvv = cvv[jabs];
      int ii0 = (t >> 6) * 8;
#pragma unroll
      for (int k = 0; k < 8; ++k) {
        int ii = ii0 + k;
        int iabs = I0 + ii;
        float a2f = (float)Pb[(size_t)iabs * NN + jabs];
        float z = a2f + rv[iabs] + gvv - CPOS2 * fabsf((float)(iabs - jabs));
        Tl[ii * 64 + jj] = EXP2F(z);
      }
    }
    __syncthreads();
    const float* Yc = Eb + (size_t)(ch * 64) * DD + d;
    for (int jg = 0; jg < 16; ++jg) {
      float y0 = Yc[(size_t)(jg * 4 + 0) * DD];
      float y1 = Yc[(size_t)(jg * 4 + 1) * DD];
      float y2 = Yc[(size_t)(jg * 4 + 2) * DD];
      float y3 = Yc[(size_t)(jg * 4 + 3) * DD];
#pragma unroll
      for (int ii = 0; ii < 32; ++ii) {
        const float4 tv = *(const float4*)&Tl[(rg * 32 + ii) * 64 + jg * 4];
        acc[ii] = fmaf(tv.x, y0, acc[ii]);
        acc[ii] = fmaf(tv.y, y1, acc[ii]);
        acc[ii] = fmaf(tv.z, y2, acc[ii]);
        acc[ii] = fmaf(tv.w, y3, acc[ii]);
      }
    }
  }
  float vs = 0.f;
#pragma unroll
  for (int ii = 0; ii < 32; ++ii) {
    int iabs = I0 + rg * 32 + ii;
    float val = Rb[(size_t)iabs * DD + d] - acc[ii] / (dn[iabs] + 1e-8f);
    vs = fmaf(val, val, vs);
  }
  vs = waveReduceSum(vs);
  int lane = t & 63, wave = t >> 6;
  if (lane == 0) red[wave] = vs;
  __syncthreads();
  if (t == 0) {
    float tot = 0.f;
    for (int w = 0; w < 8; ++w) tot += red[w];
    atomicAdd(baryAcc + b, tot);
  }
}

// ---------------- K7: xg_part[b][seg][d] = sum_{i in seg} X*r ; same for Y*c ------
__global__ __launch_bounds__(256) void xg_kernel(
    const float* __restrict__ X, const float* __restrict__ Y,
    const float* __restrict__ r, const float* __restrict__ c,
    float* __restrict__ xgp, float* __restrict__ ygp) {
  const int b = blockIdx.y, seg = blockIdx.x, d = threadIdx.x;
  float ax = 0.f, ay = 0.f;
  for (int ii = 0; ii < 256; ++ii) {
    int i = seg * 256 + ii;
    float rvv = r[b * NN + i];
    float cvv = c[b * NN + i];
    ax = fmaf(X[((size_t)b * NN + i) * DD + d], rvv, ax);
    ay = fmaf(Y[((size_t)b * NN + i) * DD + d], cvv, ay);
  }
  xgp[(size_t)(b * 4 + seg) * DD + d] = ax;
  ygp[(size_t)(b * 4 + seg) * DD + d] = ay;
}

// ---------------- K8: per-batch finalize ----------------
__global__ __launch_bounds__(256) void finalize_batch(
    const float* __restrict__ r, const float* __restrict__ c,
    const float* __restrict__ Lrow, const float* __restrict__ xgp,
    const float* __restrict__ ygp, const float* __restrict__ baryA,
    const float* __restrict__ baryB, float* __restrict__ lossArr) {
  const int b = blockIdx.x;
  const int t = threadIdx.x;
  __shared__ float sd[256];
  auto bsum = [&](float v) -> float {
    sd[t] = v; __syncthreads();
    for (int o = 128; o; o >>= 1) { if (t < o) sd[t] += sd[t + o]; __syncthreads(); }
    float res = sd[0]; __syncthreads();
    return res;
  };
  float vr = 0.f, vc = 0.f, vl = 0.f;
  for (int k = 0; k < 4; ++k) {
    int i = t + 256 * k;
    vr += r[b * NN + i];
    vc += c[b * NN + i];
    vl += Lrow[b * NN + i];
  }
  float sumR = bsum(vr);
  float sumC = bsum(vc);
  float Lmain = bsum(vl);
  float xg = (xgp[(size_t)(b * 4 + 0) * DD + t] + xgp[(size_t)(b * 4 + 1) * DD + t] +
              xgp[(size_t)(b * 4 + 2) * DD + t] + xgp[(size_t)(b * 4 + 3) * DD + t]) /
             (sumR + 1e-8f);
  float yg = (ygp[(size_t)(b * 4 + 0) * DD + t] + ygp[(size_t)(b * 4 + 1) * DD + t] +
              ygp[(size_t)(b * 4 + 2) * DD + t] + ygp[(size_t)(b * 4 + 3) * DD + t]) /
             (sumC + 1e-8f);
  float nx = bsum(xg * xg);
  float ny = bsum(yg * yg);
  float dt = bsum(xg * yg);
  if (t == 0) {
    float mx = fmaxf(sqrtf(nx), 1e-12f);
    float my = fmaxf(sqrtf(ny), 1e-12f);
    float cosv = dt / (mx * my);
    float lb = (baryA[b] + baryB[b]) * (1.0f / ((float)NN * (float)DD));
    lossArr[b] = Lmain + 0.5f * lb + 0.2f * (1.0f - cosv);
  }
}

__global__ void final_mean(const float* __restrict__ lossArr, float* __restrict__ out) {
  int t = threadIdx.x;
  float v = (t < BB) ? lossArr[t] : 0.f;
  v = waveReduceSum(v);
  if (t == 0) out[0] = v * (1.0f / BB);
}

// ---------------- launch ----------------
extern "C" void kernel_launch(void* const* d_in, const int* in_sizes, int n_in,
                              void* d_out, int out_size, void* d_ws, size_t ws_size,
                              hipStream_t stream) {
  const float* X = (const float*)d_in[0];
  const float* Y = (const float*)d_in[1];
  float* out = (float*)d_out;
  char* ws = (char*)d_ws;
  size_t off = 0;
  auto take = [&](size_t bytes) -> char* {
    char* p = ws + off;
    off = (off + bytes + 255) & ~(size_t)255;
    return p;
  };
  _Float16* Xh = (_Float16*)take((size_t)BB * NN * DD * 2);
  _Float16* Yh = (_Float16*)take((size_t)BB * NN * DD * 2);
  _Float16* A2 = (_Float16*)take((size_t)BB * NN * NN * 2);
  _Float16* A2T = (_Float16*)take((size_t)BB * NN * NN * 2);
  // zero-init region start
  size_t zstart = off;
  float* F = (float*)take((size_t)BB * NN * 4);
  float* G = (float*)take((size_t)BB * NN * 4);
  unsigned* bar = (unsigned*)take(256);
  float* baryA = (float*)take(64);
  float* baryB = (float*)take(64);
  size_t zlen = off - zstart;
  float* r = (float*)take((size_t)BB * NN * 4);
  float* c = (float*)take((size_t)BB * NN * 4);
  float* Lrow = (float*)take((size_t)BB * NN * 4);
  float* Lcol = (float*)take((size_t)BB * NN * 4);
  float* xgp = (float*)take((size_t)BB * 4 * DD * 4);
  float* ygp = (float*)take((size_t)BB * 4 * DD * 4);
  float* lossArr = (float*)take(64);
  (void)in_sizes; (void)n_in; (void)out_size; (void)ws_size;

  hipMemsetAsync(ws + zstart, 0, zlen, stream);

  normalize_kernel<<<dim3(2 * BB * NN / 4), dim3(256), 0, stream>>>(X, Y, Xh, Yh);
  gemm_a2_kernel<<<dim3(NN / 128, NN / 128, BB), dim3(256), 0, stream>>>(Xh, Yh, A2);
  gemm_a2_kernel<<<dim3(NN / 128, NN / 128, BB), dim3(256), 0, stream>>>(Yh, Xh, A2T);
  sinkhorn_kernel<<<dim3(256), dim3(512), 0, stream>>>(A2, A2T, F, G, bar);
  marginals_kernel<<<dim3(8, BB), dim3(512), 0, stream>>>(A2, F, G, r, Lrow);
  marginals_kernel<<<dim3(8, BB), dim3(512), 0, stream>>>(A2T, G, F, c, Lcol);
  bary_kernel<<<dim3(NN / 64, BB), dim3(512), 0, stream>>>(A2, F, G, r, Y, X, baryA);
  bary_kernel<<<dim3(NN / 64, BB), dim3(512), 0, stream>>>(A2T, G, F, c, X, Y, baryB);
  xg_kernel<<<dim3(4, BB), dim3(256), 0, stream>>>(X, Y, r, c, xgp, ygp);
  finalize_batch<<<dim3(BB), dim3(256), 0, stream>>>(r, c, Lrow, xgp, ygp, baryA, baryB, lossArr);
  final_mean<<<dim3(1), dim3(64), 0, stream>>>(lossArr, out);
}